// Round 1
// baseline (492.351 us; speedup 1.0000x reference)
//
#include <hip/hip_runtime.h>
#include <hip/hip_bf16.h>
#include <math.h>

typedef __bf16 bf16_t;
typedef __bf16 bf16x4 __attribute__((ext_vector_type(4)));
typedef __bf16 bf16x8 __attribute__((ext_vector_type(8)));
typedef float  f32x4  __attribute__((ext_vector_type(4)));

#define NROWS 50000

// ---------------- weight permutation (coalesced reads, scattered 8B writes) ----------------
// permW1[kt 0..31][q 0..3][row 0..511][8] = fcW[row][kt*32+q*8+j]
// permB2[kt 0..15][q 0..3][r 0..511][8]   = interleaved a/b rows
__global__ void k_convert(const float* __restrict__ fcW,
                          const float* __restrict__ aW,
                          const float* __restrict__ bW,
                          const float* __restrict__ clsW,
                          const float* __restrict__ instW,
                          bf16_t* __restrict__ permW1, bf16_t* __restrict__ permB2,
                          bf16_t* __restrict__ clsWb, bf16_t* __restrict__ instWb) {
    int t = blockIdx.x * 256 + threadIdx.x;
    if (t < 131072) {
        float4 v = *(const float4*)(fcW + (long)t * 4);
        int row = t >> 8;
        int k0 = (t & 255) * 4;
        int kt = k0 >> 5, q = (k0 >> 3) & 3, j = k0 & 7;
        bf16_t o[4] = {(bf16_t)v.x, (bf16_t)v.y, (bf16_t)v.z, (bf16_t)v.w};
        *(bf16x4*)(permW1 + kt * 16384 + q * 4096 + row * 8 + j) = *(bf16x4*)o;
    } else if (t < 196608) {
        int t2 = t - 131072;
        int isB = t2 >> 15;
        int f = t2 & 32767;
        float4 v = *(const float4*)(((isB ? bW : aW)) + (long)f * 4);
        int srow = f >> 7;
        int k0 = (f & 127) * 4;
        int kt = k0 >> 5, q = (k0 >> 3) & 3, j = k0 & 7;
        int r = ((srow >> 4) * 2 + isB) * 16 + (srow & 15);
        bf16_t o[4] = {(bf16_t)v.x, (bf16_t)v.y, (bf16_t)v.z, (bf16_t)v.w};
        *(bf16x4*)(permB2 + kt * 16384 + q * 4096 + r * 8 + j) = *(bf16x4*)o;
    } else if (t < 197632) {
        int i = t - 196608;     // 0..1023
        clsWb[i] = (bf16_t)clsW[i];
    } else if (t < 198656) {
        int i = t - 197632;     // 0..1023
        instWb[i] = (bf16_t)instW[i];
    }
}

// ---------------- fused: GEMM1 (x@W1^T,relu) -> hh in LDS -> GEMM2 + att + cls + inst ----
// 512 threads = 8 waves (wr 0..1, wc 0..3). Block owns 128 rows exclusively.
// LDS: x-stage dbuf 2x8192 @0 ; hh tile [128][520] bf16 @16384 (133120 B) = 149504 total.
// W1/W2/cls/inst weights stream L2 -> registers (no LDS, no staging barriers in phase B).
__global__ __launch_bounds__(512, 2) void k_fused(
        const float* __restrict__ x,
        const bf16_t* __restrict__ permW1, const bf16_t* __restrict__ permB2,
        const bf16_t* __restrict__ clsWb, const bf16_t* __restrict__ instWb,
        const float* __restrict__ fcb,
        const float* __restrict__ aab, const float* __restrict__ abb,
        const float* __restrict__ acW, const float* __restrict__ acb,
        const float* __restrict__ clsb, const float* __restrict__ instb,
        float* __restrict__ Araw, float* __restrict__ inst,
        float* __restrict__ instLog) {
    __shared__ __align__(16) char smem[149504];
    bf16_t* hhT = (bf16_t*)(smem + 16384);   // [128][520] bf16, stride 520 (=65*16B aligned, bank-staggered)

    const int tid = threadIdx.x;
    const int w = tid >> 6, l = tid & 63, q = l >> 4, li = l & 15;
    const int wr = w >> 2, wc = w & 3;
    const long row0 = (long)blockIdx.x * 128;

    f32x4 acc[4][8];
    #pragma unroll
    for (int a = 0; a < 4; a++)
        #pragma unroll
        for (int c = 0; c < 8; c++) acc[a][c] = (f32x4)0.0f;

    // ================= phase A: hh = relu(x @ W1^T + fcb) =================
    int arow[2], akx[2]; bool av[2];
    #pragma unroll
    for (int j = 0; j < 2; j++) {
        int s = j * 512 + tid;
        arow[j] = s >> 3; akx[j] = s & 7;
        av[j] = (row0 + arow[j]) < NROWS;
    }
    const float* xb = x + row0 * 1024;

    float4 xv[2];
    #pragma unroll
    for (int j = 0; j < 2; j++)
        xv[j] = av[j] ? *(const float4*)(xb + (long)arow[j] * 1024 + akx[j] * 4)
                      : make_float4(0.f, 0.f, 0.f, 0.f);
    #pragma unroll
    for (int j = 0; j < 2; j++) {
        bf16_t o[4] = {(bf16_t)xv[j].x, (bf16_t)xv[j].y, (bf16_t)xv[j].z, (bf16_t)xv[j].w};
        *(bf16x4*)(smem + (akx[j] >> 1) * 2048 + arow[j] * 16 + (akx[j] & 1) * 8) = *(bf16x4*)o;
    }
    #pragma unroll
    for (int j = 0; j < 2; j++)
        xv[j] = av[j] ? *(const float4*)(xb + (long)arow[j] * 1024 + 32 + akx[j] * 4)
                      : make_float4(0.f, 0.f, 0.f, 0.f);
    __syncthreads();

    for (int kt = 0; kt < 32; kt++) {
        const int cur = kt & 1, nxt = cur ^ 1;
        if (kt < 31) {
            #pragma unroll
            for (int j = 0; j < 2; j++) {
                bf16_t o[4] = {(bf16_t)xv[j].x, (bf16_t)xv[j].y, (bf16_t)xv[j].z, (bf16_t)xv[j].w};
                *(bf16x4*)(smem + nxt * 8192 + (akx[j] >> 1) * 2048 + arow[j] * 16 + (akx[j] & 1) * 8) = *(bf16x4*)o;
            }
            int kn = (kt < 30 ? kt + 2 : 31) * 32;
            #pragma unroll
            for (int j = 0; j < 2; j++)
                xv[j] = av[j] ? *(const float4*)(xb + (long)arow[j] * 1024 + kn + akx[j] * 4)
                              : make_float4(0.f, 0.f, 0.f, 0.f);
        }
        const bf16_t* Ab = (const bf16_t*)(smem + cur * 8192);
        const bf16_t* Bg = permW1 + kt * 16384 + q * 4096;
        bf16x8 bfr[8], afr[4];
        #pragma unroll
        for (int tn = 0; tn < 8; tn++)
            bfr[tn] = *(const bf16x8*)(Bg + (wc * 128 + tn * 16 + li) * 8);
        #pragma unroll
        for (int tm = 0; tm < 4; tm++)
            afr[tm] = *(const bf16x8*)(Ab + q * 1024 + (wr * 64 + tm * 16 + li) * 8);
        #pragma unroll
        for (int tm = 0; tm < 4; tm++)
            #pragma unroll
            for (int tn = 0; tn < 8; tn++)
                acc[tm][tn] = __builtin_amdgcn_mfma_f32_16x16x32_bf16(afr[tm], bfr[tn], acc[tm][tn], 0, 0, 0);
        __syncthreads();
    }

    // ---- epilogue A: bias + relu, write hh tile to LDS ----
    {
        float bias[8];
        #pragma unroll
        for (int tn = 0; tn < 8; tn++) bias[tn] = fcb[wc * 128 + tn * 16 + li];
        #pragma unroll
        for (int tm = 0; tm < 4; tm++)
            #pragma unroll
            for (int tn = 0; tn < 8; tn++)
                #pragma unroll
                for (int r = 0; r < 4; r++) {
                    float v = acc[tm][tn][r] + bias[tn];
                    v = v > 0.f ? v : 0.f;
                    hhT[(wr * 64 + tm * 16 + q * 4 + r) * 520 + wc * 128 + tn * 16 + li] = (bf16_t)v;
                }
    }
    __syncthreads();

    // ================= phase B: [a|b] = hh @ W2^T (+ cls/inst partials), barrier-free ======
    #pragma unroll
    for (int a = 0; a < 4; a++)
        #pragma unroll
        for (int c = 0; c < 8; c++) acc[a][c] = (f32x4)0.0f;
    float c0[4] = {0,0,0,0}, c1[4] = {0,0,0,0}, c2[4] = {0,0,0,0}, c3[4] = {0,0,0,0};

    for (int kt = 0; kt < 16; kt++) {
        const bf16_t* Bg = permB2 + kt * 16384 + q * 4096;
        bf16x8 bfr[8], afr[4];
        #pragma unroll
        for (int tn = 0; tn < 8; tn++)
            bfr[tn] = *(const bf16x8*)(Bg + (wc * 128 + tn * 16 + li) * 8);
        #pragma unroll
        for (int tm = 0; tm < 4; tm++)
            afr[tm] = *(const bf16x8*)(hhT + (wr * 64 + tm * 16 + li) * 520 + kt * 32 + q * 8);
        #pragma unroll
        for (int tm = 0; tm < 4; tm++)
            #pragma unroll
            for (int tn = 0; tn < 8; tn++)
                acc[tm][tn] = __builtin_amdgcn_mfma_f32_16x16x32_bf16(afr[tm], bfr[tn], acc[tm][tn], 0, 0, 0);
        if ((kt >> 2) == wc) {   // each wc covers 4 of the 16 k-steps for cls+inst heads
            bf16x8 w0 = *(const bf16x8*)(clsWb + kt * 32 + q * 8);
            bf16x8 w1 = *(const bf16x8*)(clsWb + 512 + kt * 32 + q * 8);
            bf16x8 w2 = *(const bf16x8*)(instWb + kt * 32 + q * 8);
            bf16x8 w3 = *(const bf16x8*)(instWb + 512 + kt * 32 + q * 8);
            #pragma unroll
            for (int tm = 0; tm < 4; tm++) {
                float s0 = 0.f, s1 = 0.f, s2 = 0.f, s3 = 0.f;
                #pragma unroll
                for (int jj = 0; jj < 8; jj++) {
                    float a = (float)afr[tm][jj];
                    s0 += a * (float)w0[jj];
                    s1 += a * (float)w1[jj];
                    s2 += a * (float)w2[jj];
                    s3 += a * (float)w3[jj];
                }
                c0[tm] += s0; c1[tm] += s1; c2[tm] += s2; c3[tm] += s3;
            }
        }
    }

    // ---- epilogue B: att(tanh*sigmoid*cW) row-reduce, cls/inst reduce, direct stores ----
    float (*apart)[4]      = (float (*)[4])smem;               // [128][4] @0 (x-stage area is dead)
    float (*cpart)[128][4] = (float (*)[128][4])(smem + 2048); // [4][128][4]

    float sum_mr[4][4];
    #pragma unroll
    for (int a = 0; a < 4; a++)
        #pragma unroll
        for (int c = 0; c < 4; c++) sum_mr[a][c] = 0.f;
    #pragma unroll
    for (int p = 0; p < 4; p++) {
        int j = (wc * 4 + p) * 16 + li;     // feature 0..255
        float ab_ = aab[j], bb_ = abb[j], cw = acW[j];
        #pragma unroll
        for (int tm = 0; tm < 4; tm++)
            #pragma unroll
            for (int r = 0; r < 4; r++) {
                float avv = tanhf(acc[tm][2 * p][r] + ab_);
                float bvv = acc[tm][2 * p + 1][r] + bb_;
                bvv = 1.f / (1.f + expf(-bvv));
                sum_mr[tm][r] += avv * bvv * cw;
            }
    }
    #pragma unroll
    for (int tm = 0; tm < 4; tm++)
        #pragma unroll
        for (int r = 0; r < 4; r++) {
            float v = sum_mr[tm][r];
            v += __shfl_xor(v, 1); v += __shfl_xor(v, 2);
            v += __shfl_xor(v, 4); v += __shfl_xor(v, 8);
            if (li == 0) apart[wr * 64 + tm * 16 + q * 4 + r][wc] = v;
        }
    #pragma unroll
    for (int tm = 0; tm < 4; tm++) {
        float v0 = c0[tm], v1 = c1[tm], v2 = c2[tm], v3 = c3[tm];
        v0 += __shfl_xor(v0, 16); v0 += __shfl_xor(v0, 32);
        v1 += __shfl_xor(v1, 16); v1 += __shfl_xor(v1, 32);
        v2 += __shfl_xor(v2, 16); v2 += __shfl_xor(v2, 32);
        v3 += __shfl_xor(v3, 16); v3 += __shfl_xor(v3, 32);
        if (l < 16) {
            float* cp = cpart[wc][wr * 64 + tm * 16 + li];
            cp[0] = v0; cp[1] = v1; cp[2] = v2; cp[3] = v3;
        }
    }
    __syncthreads();

    if (tid < 128) {
        long g = row0 + tid;
        if (g < NROWS) {
            float s = apart[tid][0] + apart[tid][1] + apart[tid][2] + apart[tid][3] + acb[0];
            Araw[g] = s;
            float o0 = clsb[0], o1 = clsb[1], o2 = instb[0], o3 = instb[1];
            #pragma unroll
            for (int k = 0; k < 4; k++) {
                o0 += cpart[k][tid][0]; o1 += cpart[k][tid][1];
                o2 += cpart[k][tid][2]; o3 += cpart[k][tid][3];
            }
            inst[g * 2]     = o0; inst[g * 2 + 1]     = o1;
            instLog[g * 2]  = o2; instLog[g * 2 + 1]  = o3;
        }
    }
}

// ---------------- top-8/bottom-8 partials: 8 blocks (4 quarters x 2 passes) ----------------
__global__ void k_topk_part(const float* __restrict__ scores,
                            float* __restrict__ candV, int* __restrict__ candI,
                            float* __restrict__ sums) {
    __shared__ float cv[4096];
    __shared__ int   ci[4096];
    int tid = threadIdx.x;        // 512
    int p = blockIdx.x;           // 0..7
    int pass = p & 1, rq = p >> 1;
    if (p == 0 && tid == 0) { sums[0] = 0.f; sums[1] = 0.f; sums[2] = 0.f; }
    float sign = pass ? -1.f : 1.f;
    int lo = rq * 12500, hi = lo + 12500;
    float tv[8]; int ti[8];
    #pragma unroll
    for (int k = 0; k < 8; k++) { tv[k] = -1e30f; ti[k] = 0x7fffffff; }
    for (int i = lo + tid; i < hi; i += 512) {
        float v = sign * scores[i];
        if (v > tv[7] || (v == tv[7] && i < ti[7])) {
            int k = 7;
            while (k > 0 && (v > tv[k-1] || (v == tv[k-1] && i < ti[k-1]))) {
                tv[k] = tv[k-1]; ti[k] = ti[k-1]; k--;
            }
            tv[k] = v; ti[k] = i;
        }
    }
    #pragma unroll
    for (int k = 0; k < 8; k++) { cv[tid * 8 + k] = tv[k]; ci[tid * 8 + k] = ti[k]; }
    __syncthreads();
    if (tid < 64) {
        float mv[8]; int mi[8];
        #pragma unroll
        for (int k = 0; k < 8; k++) { mv[k] = -1e30f; mi[k] = 0x7fffffff; }
        for (int i = 0; i < 64; i++) {
            int slot = tid * 64 + ((i + tid) & 63);   // lane-rotated: spread banks
            float v = cv[slot]; int idx = ci[slot];
            #pragma unroll
            for (int k = 0; k < 8; k++) {
                bool bt = (v > mv[k]) || (v == mv[k] && idx < mi[k]);
                float nv = bt ? v : mv[k];  int ni = bt ? idx : mi[k];
                float ov = bt ? mv[k] : v;  int oi = bt ? mi[k] : idx;
                mv[k] = nv; mi[k] = ni; v = ov; idx = oi;
            }
        }
        for (int r = 0; r < 8; r++) {
            float bv = mv[0]; int bi = mi[0]; int bs = tid;
            for (int m = 1; m < 64; m <<= 1) {
                float ov = __shfl_xor(bv, m); int oi = __shfl_xor(bi, m); int os = __shfl_xor(bs, m);
                if (ov > bv || (ov == bv && oi < bi)) { bv = ov; bi = oi; bs = os; }
            }
            if (tid == 0) {
                candV[pass * 32 + rq * 8 + r] = bv;
                candI[pass * 32 + rq * 8 + r] = bi;
            }
            if (tid == bs) {
                #pragma unroll
                for (int k = 0; k < 7; k++) { mv[k] = mv[k+1]; mi[k] = mi[k+1]; }
                mv[7] = -1e30f; mi[7] = 0x7fffffff;
            }
        }
    }
}

// ---------------- softmax-weighted sums (max = best quarter top-1) ----------------
__global__ void k_sum(const float* __restrict__ Araw, const float* __restrict__ inst,
                      const float* __restrict__ candV, float* sums) {
    __shared__ float r0[4], r1[4], r2[4];
    int tid = threadIdx.x;
    float mx = -1e30f;
    #pragma unroll
    for (int p = 0; p < 4; p++) mx = fmaxf(mx, candV[p * 8]);
    float se = 0.f, s0 = 0.f, s1 = 0.f;
    for (int i = blockIdx.x * 256 + tid; i < NROWS; i += 32768) {
        float e = expf(Araw[i] - mx);
        se += e; s0 += inst[2 * i] * e; s1 += inst[2 * i + 1] * e;
    }
    for (int s = 1; s < 64; s <<= 1) {
        se += __shfl_xor(se, s); s0 += __shfl_xor(s0, s); s1 += __shfl_xor(s1, s);
    }
    if ((tid & 63) == 0) { r0[tid >> 6] = se; r1[tid >> 6] = s0; r2[tid >> 6] = s1; }
    __syncthreads();
    if (tid == 0) {
        atomicAdd(&sums[0], r0[0] + r0[1] + r0[2] + r0[3]);
        atomicAdd(&sums[1], r1[0] + r1[1] + r1[2] + r1[3]);
        atomicAdd(&sums[2], r2[0] + r2[1] + r2[2] + r2[3]);
    }
}

// ---------------- finalize: merge 32+32 candidates, preds + instance_loss from logits ----
__global__ void k_fin(const float* __restrict__ instLog,
                      const float* __restrict__ candV, const int* __restrict__ candI,
                      const float* __restrict__ sums, float* __restrict__ dout) {
    __shared__ int mid[16];
    int tid = threadIdx.x;          // 128
    int wv = tid >> 6, l = tid & 63;
    if (wv < 2) {
        float v; int idx;
        if (l < 32) { v = candV[wv * 32 + l]; idx = candI[wv * 32 + l]; }
        else        { v = -1e30f; idx = 0x7fffffff; }
        for (int r = 0; r < 8; r++) {
            float bv = v; int bi = idx; int bs = l;
            for (int m = 1; m < 64; m <<= 1) {
                float ov = __shfl_xor(bv, m); int oi = __shfl_xor(bi, m); int os = __shfl_xor(bs, m);
                if (ov > bv || (ov == bv && oi < bi)) { bv = ov; bi = oi; bs = os; }
            }
            if (l == 0) mid[wv * 8 + r] = bi;
            if (l == bs) { v = -1e30f; idx = 0x7fffffff; }
        }
    }
    __syncthreads();
    if (tid < 16) {
        int id = mid[tid];
        float l0 = instLog[id * 2], l1 = instLog[id * 2 + 1];
        float mx = fmaxf(l0, l1);
        float lse = mx + logf(expf(l0 - mx) + expf(l1 - mx));
        float lt = (tid < 8) ? l1 : l0;
        float term = lse - lt;
        for (int m = 1; m < 16; m <<= 1) term += __shfl_xor(term, m);
        if (tid == 0) {
            dout[150002] = term / 16.f;
            float se = sums[0];
            dout[0] = sums[1] / se;
            dout[1] = sums[2] / se;
        }
    }
}

extern "C" void kernel_launch(void* const* d_in, const int* in_sizes, int n_in,
                              void* d_out, int out_size, void* d_ws, size_t ws_size,
                              hipStream_t stream) {
    const float* h   = (const float*)d_in[0];
    const float* fcW = (const float*)d_in[1];
    const float* fcb = (const float*)d_in[2];
    const float* aaW = (const float*)d_in[3];
    const float* aab = (const float*)d_in[4];
    const float* abW = (const float*)d_in[5];
    const float* abb = (const float*)d_in[6];
    const float* acW = (const float*)d_in[7];
    const float* acb = (const float*)d_in[8];
    const float* clW = (const float*)d_in[9];
    const float* clb = (const float*)d_in[10];
    const float* inW = (const float*)d_in[11];
    const float* inb = (const float*)d_in[12];
    float* out = (float*)d_out;

    char* ws = (char*)d_ws;
    bf16_t* permW1  = (bf16_t*)(ws);                       // 1,048,576 B
    bf16_t* permB2  = (bf16_t*)(ws + 1048576);             // 524,288 B
    bf16_t* clsWb   = (bf16_t*)(ws + 1572864);             // 2,048 B
    bf16_t* instWb  = (bf16_t*)(ws + 1574912);             // 2,048 B
    float*  instLog = (float*) (ws + 1576960);             // 400,000 B
    float*  candV   = (float*) (ws + 1976960);             // 256 B
    int*    candI   = (int*)   (ws + 1977216);             // 256 B
    float*  sums    = (float*) (ws + 1977472);             // 16 B

    float* inst = out + 2;
    float* Araw = out + 2 + 100000;

    k_convert<<<776, 256, 0, stream>>>(fcW, aaW, abW, clW, inW, permW1, permB2, clsWb, instWb);
    k_fused<<<391, 512, 0, stream>>>(h, permW1, permB2, clsWb, instWb,
                                     fcb, aab, abb, acW, acb, clb, inb,
                                     Araw, inst, instLog);
    k_topk_part<<<8, 512, 0, stream>>>(Araw, candV, candI, sums);
    k_sum<<<128, 256, 0, stream>>>(Araw, inst, candV, sums);
    k_fin<<<1, 128, 0, stream>>>(instLog, candV, candI, sums, out);
}